// Round 6
// baseline (86.201 us; speedup 1.0000x reference)
//
#include <hip/hip_runtime.h>

typedef float  f32x4  __attribute__((ext_vector_type(4)));
typedef short  s16x8  __attribute__((ext_vector_type(8)));

#define NROWS (2048 * 128)
#define PASSES 2         // 32-sample passes per wave
#define EPSF 1e-8f

union Frag { s16x8 v; unsigned short u[8]; unsigned int w[4]; };

// fp32 -> bf16 RTNE (verified R3-R5)
__device__ __forceinline__ unsigned short f2bf(float f) {
    unsigned int u = __float_as_uint(f);
    u += 0x7fffu + ((u >> 16) & 1u);
    return (unsigned short)(u >> 16);
}
// pack two fp32 -> dword of 2 bf16 (lo = a, hi = b), RTNE
__device__ __forceinline__ unsigned int pk2(float a, float b) {
    unsigned int ua = __float_as_uint(a);
    ua += 0x7fffu + ((ua >> 16) & 1u);
    unsigned int ub = __float_as_uint(b);
    ub += 0x7fffu + ((ub >> 16) & 1u);
    return (ua >> 16) | (ub & 0xffff0000u);
}

// ---------------------------------------------------------------------------
// Pre-kernel: repack weights (unchanged from R5 — A-frag layout == old B-frag
// layout per-lane: lane l holds W[out = base + (l&15)][k = (l>>4)*8 + j]).
// Contiguous in ws: w1(24576) w2(15360) w3(12288) b1(384) b2(320) b3(256).
// ---------------------------------------------------------------------------
__global__ void repack(const float* __restrict__ W1, const float* __restrict__ b1,
                       const float* __restrict__ W2, const float* __restrict__ b2,
                       const float* __restrict__ W3, const float* __restrict__ b3,
                       unsigned short* __restrict__ w1f, unsigned short* __restrict__ w2f,
                       unsigned short* __restrict__ w3f,
                       float* __restrict__ b1p, float* __restrict__ b2p,
                       float* __restrict__ b3p)
{
    const int b = blockIdx.x;
    const int l = threadIdx.x;      // 64 threads
    const int g = l >> 4, sl = l & 15;

    if (b < 24) {                   // W1: nt = b>>2, ks = b&3
        const int nt = b >> 2, ks = b & 3;
        const int o = nt * 16 + sl, kb = ks * 32 + g * 8;
        s16x8 v;
#pragma unroll
        for (int j = 0; j < 8; ++j) v[j] = (short)f2bf(W1[o * 128 + kb + j]);
        *(s16x8*)&w1f[b * 512 + l * 8] = v;
    } else if (b < 39) {            // W2 (out padded 72->80 with zero rows)
        const int f = b - 24, nt = f / 3, ks = f % 3;
        const int o = nt * 16 + sl, kb = ks * 32 + g * 8;
        s16x8 v;
#pragma unroll
        for (int j = 0; j < 8; ++j)
            v[j] = (short)((o < 72) ? f2bf(W2[o * 96 + kb + j]) : 0);
        *(s16x8*)&w2f[f * 512 + l * 8] = v;
    } else if (b < 51) {            // W3 (k padded 72->96 with zeros)
        const int f = b - 39, nt = f / 3, ks = f % 3;
        const int o = nt * 16 + sl, kb = ks * 32 + g * 8;
        s16x8 v;
#pragma unroll
        for (int j = 0; j < 8; ++j)
            v[j] = (short)((kb + j < 72) ? f2bf(W3[o * 72 + kb + j]) : 0);
        *(s16x8*)&w3f[f * 512 + l * 8] = v;
    } else {                        // biases, zero-padded
        for (int i = l; i < 240; i += 64) {
            if (i < 96)       b1p[i] = b1[i];
            else if (i < 176) { int o = i - 96; b2p[o] = (o < 72) ? b2[o] : 0.f; }
            else              b3p[i - 176] = b3[i - 176];
        }
    }
}

// ---------------------------------------------------------------------------
// Main. Swapped GEMM: D[out][sample] = W x h^T.  A = W frag (LDS b128),
// B = activation frag.  Inter-layer transfer is pure-register:
//   producer: lane (g,sl) holds feat nt*16+g*4+r of sample sl (D regs)
//   consumer: lane (g,sl) needs feats ks*32+g*8+j of sample sl (B-frag)
//   word w of frag ks = P[nt=2ks+(lane&32?1:0)][w&1] from lane (2(g&1)+(w>>1))*16+sl
// No activation LDS at all -> 54.2 KB LDS -> 3 blocks/CU, 12 waves/CU.
// ---------------------------------------------------------------------------
__global__ __launch_bounds__(256, 3)
void mlp_main(const float* __restrict__ x,
              const f32x4* __restrict__ wsrc,   // 3324 x 16 B
              float* __restrict__ acc /* [65]: s[64], uu */)
{
    __shared__ __align__(16) unsigned char wb[53184];
    __shared__ __align__(16) float sred[4][64];
    __shared__ float uured[4];

    const unsigned short* w1L = (const unsigned short*)wb;   // 24 frags
    const unsigned short* w2L = w1L + 12288;                 // 15 frags
    const unsigned short* w3L = w1L + 19968;                 // 12 frags
    const float* b1L = (const float*)(wb + 52224);           // 96
    const float* b2L = b1L + 96;                             // 80
    const float* b3L = b1L + 176;                            // 64

    const int tid  = threadIdx.x;
    const int lane = tid & 63;
    const int wv   = tid >> 6;
    const int sl   = lane & 15;
    const int g4   = (lane >> 2) & 12;                // g*4
    const int srcA = ((lane & 16) << 1) | sl;         // (2*(g&1)+0)*16 + sl
    const int srcB = srcA + 16;                       // hi = 1

    const int wave_gid = blockIdx.x * 4 + wv;

    // per-lane x gather: sample = base + st*16 + sl, cols ks*32 + g*8 + 0..7
    auto loadx = [&](f32x4 (&xp)[16], int p) {
        const float* xw = x + (size_t)(wave_gid * PASSES + p) * 32 * 128;
#pragma unroll
        for (int st = 0; st < 2; ++st)
#pragma unroll
            for (int ks = 0; ks < 4; ++ks) {
                const float* ptr = xw + (st * 16 + sl) * 128 + ks * 32 + ((lane >> 1) & 24);
                xp[st * 8 + ks * 2 + 0] = *(const f32x4*)ptr;
                xp[st * 8 + ks * 2 + 1] = *(const f32x4*)(ptr + 4);
            }
    };

    f32x4 xp[16];
    loadx(xp, 0);                         // overlap with weight staging

    for (int i = tid; i < 3324; i += 256)
        ((f32x4*)wb)[i] = wsrc[i];
    __syncthreads();

    float s_acc[4][4];
#pragma unroll
    for (int nt = 0; nt < 4; ++nt)
#pragma unroll
        for (int r = 0; r < 4; ++r) s_acc[nt][r] = 0.f;
    float uu_acc = 0.f;

#pragma unroll
    for (int p = 0; p < PASSES; ++p) {
        // ---- x B-frags ----
        Frag Bx[2][4];
#pragma unroll
        for (int st = 0; st < 2; ++st)
#pragma unroll
            for (int ks = 0; ks < 4; ++ks)
#pragma unroll
                for (int j = 0; j < 4; ++j) {
                    Bx[st][ks].u[j]     = f2bf(xp[st * 8 + ks * 2 + 0][j]);
                    Bx[st][ks].u[4 + j] = f2bf(xp[st * 8 + ks * 2 + 1][j]);
                }

        // ================= layer 1: 128 -> 96 =================
        f32x4 D1[2][6];
#pragma unroll
        for (int nt = 0; nt < 6; ++nt) {
            const f32x4 bb = *(const f32x4*)&b1L[nt * 16 + g4];
            D1[0][nt] = bb; D1[1][nt] = bb;
        }
#pragma unroll
        for (int ks = 0; ks < 4; ++ks)
#pragma unroll
            for (int nt = 0; nt < 6; ++nt) {
                const s16x8 A = *(const s16x8*)&w1L[(nt * 4 + ks) * 512 + lane * 8];
                D1[0][nt] = __builtin_amdgcn_mfma_f32_16x16x32_bf16(A, Bx[0][ks].v, D1[0][nt], 0, 0, 0);
                D1[1][nt] = __builtin_amdgcn_mfma_f32_16x16x32_bf16(A, Bx[1][ks].v, D1[1][nt], 0, 0, 0);
            }

        // ---- transition 1: relu+pack+shuffle -> F2 (h1, 96 feats) ----
        Frag F2[2][3];
#pragma unroll
        for (int st = 0; st < 2; ++st) {
            unsigned int P[6][2], R[6][2][2];
#pragma unroll
            for (int nt = 0; nt < 6; ++nt) {
                P[nt][0] = pk2(fmaxf(D1[st][nt][0], 0.f), fmaxf(D1[st][nt][1], 0.f));
                P[nt][1] = pk2(fmaxf(D1[st][nt][2], 0.f), fmaxf(D1[st][nt][3], 0.f));
            }
#pragma unroll
            for (int nt = 0; nt < 6; ++nt)
#pragma unroll
                for (int q = 0; q < 2; ++q) {
                    R[nt][q][0] = __shfl(P[nt][q], srcA, 64);
                    R[nt][q][1] = __shfl(P[nt][q], srcB, 64);
                }
#pragma unroll
            for (int ks = 0; ks < 3; ++ks)
#pragma unroll
                for (int w = 0; w < 4; ++w)
                    F2[st][ks].w[w] = (lane & 32) ? R[2 * ks + 1][w & 1][w >> 1]
                                                  : R[2 * ks][w & 1][w >> 1];
        }

        // prefetch next pass's x (D1/xp dead; window = L2+L3+epilogue)
        if (p + 1 < PASSES) loadx(xp, p + 1);

        // ================= layer 2: 96 -> 72 (pad 80) =================
        f32x4 D2[2][5];
#pragma unroll
        for (int nt = 0; nt < 5; ++nt) {
            const f32x4 bb = *(const f32x4*)&b2L[nt * 16 + g4];
            D2[0][nt] = bb; D2[1][nt] = bb;
        }
#pragma unroll
        for (int ks = 0; ks < 3; ++ks)
#pragma unroll
            for (int nt = 0; nt < 5; ++nt) {
                const s16x8 A = *(const s16x8*)&w2L[(nt * 3 + ks) * 512 + lane * 8];
                D2[0][nt] = __builtin_amdgcn_mfma_f32_16x16x32_bf16(A, F2[0][ks].v, D2[0][nt], 0, 0, 0);
                D2[1][nt] = __builtin_amdgcn_mfma_f32_16x16x32_bf16(A, F2[1][ks].v, D2[1][nt], 0, 0, 0);
            }

        // ---- transition 2: h2 (80 real feats, 80..95 zero) -> F3 ----
        Frag F3[2][3];
#pragma unroll
        for (int st = 0; st < 2; ++st) {
            unsigned int P[5][2], R[5][2][2];
#pragma unroll
            for (int nt = 0; nt < 5; ++nt) {
                P[nt][0] = pk2(fmaxf(D2[st][nt][0], 0.f), fmaxf(D2[st][nt][1], 0.f));
                P[nt][1] = pk2(fmaxf(D2[st][nt][2], 0.f), fmaxf(D2[st][nt][3], 0.f));
            }
#pragma unroll
            for (int nt = 0; nt < 5; ++nt)
#pragma unroll
                for (int q = 0; q < 2; ++q) {
                    R[nt][q][0] = __shfl(P[nt][q], srcA, 64);
                    R[nt][q][1] = __shfl(P[nt][q], srcB, 64);
                }
#pragma unroll
            for (int ks = 0; ks < 3; ++ks)
#pragma unroll
                for (int w = 0; w < 4; ++w) {
                    const unsigned int hi =
                        (2 * ks + 1 < 5) ? R[2 * ks + 1][w & 1][w >> 1] : 0u;
                    F3[st][ks].w[w] = (lane & 32) ? hi : R[2 * ks][w & 1][w >> 1];
                }
        }

        // ================= layer 3: 96 (h2 padded) -> 64 =================
        f32x4 D3[2][4];
#pragma unroll
        for (int nt = 0; nt < 4; ++nt) {
            const f32x4 bb = *(const f32x4*)&b3L[nt * 16 + g4];
            D3[0][nt] = bb; D3[1][nt] = bb;
        }
#pragma unroll
        for (int ks = 0; ks < 3; ++ks)
#pragma unroll
            for (int nt = 0; nt < 4; ++nt) {
                const s16x8 A = *(const s16x8*)&w3L[(nt * 3 + ks) * 512 + lane * 8];
                D3[0][nt] = __builtin_amdgcn_mfma_f32_16x16x32_bf16(A, F3[0][ks].v, D3[0][nt], 0, 0, 0);
                D3[1][nt] = __builtin_amdgcn_mfma_f32_16x16x32_bf16(A, F3[1][ks].v, D3[1][nt], 0, 0, 0);
            }

        // ===== epilogue: lane (g,sl) holds f[nt*16+g*4+r][sample=sl] =====
#pragma unroll
        for (int st = 0; st < 2; ++st) {
            float ff = 0.f;
#pragma unroll
            for (int nt = 0; nt < 4; ++nt)
#pragma unroll
                for (int r = 0; r < 4; ++r)
                    ff = fmaf(D3[st][nt][r], D3[st][nt][r], ff);
            ff += __shfl_xor(ff, 16, 64);      // sum over g: full ||f||^2[sl]
            ff += __shfl_xor(ff, 32, 64);
            const float inv = 1.f / fmaxf(sqrtf(ff), EPSF);
            uu_acc = fmaf(ff * inv, inv, uu_acc);     // x4 dup over g
#pragma unroll
            for (int nt = 0; nt < 4; ++nt)
#pragma unroll
                for (int r = 0; r < 4; ++r)
                    s_acc[nt][r] = fmaf(D3[st][nt][r], inv, s_acc[nt][r]);
        }
    }

    // ---- once per wave: reduce s over sl lanes, uu over all lanes ----
#pragma unroll
    for (int nt = 0; nt < 4; ++nt)
#pragma unroll
        for (int r = 0; r < 4; ++r) {
            s_acc[nt][r] += __shfl_xor(s_acc[nt][r], 1, 64);
            s_acc[nt][r] += __shfl_xor(s_acc[nt][r], 2, 64);
            s_acc[nt][r] += __shfl_xor(s_acc[nt][r], 4, 64);
            s_acc[nt][r] += __shfl_xor(s_acc[nt][r], 8, 64);
        }
#pragma unroll
    for (int off = 1; off < 64; off <<= 1)
        uu_acc += __shfl_xor(uu_acc, off, 64);

    if (sl == 0) {                 // 4 lanes (g=0..3): s[out = nt*16+g*4+r]
#pragma unroll
        for (int nt = 0; nt < 4; ++nt) {
            f32x4 v = {s_acc[nt][0], s_acc[nt][1], s_acc[nt][2], s_acc[nt][3]};
            *(f32x4*)&sred[wv][nt * 16 + g4] = v;
        }
    }
    if (lane == 0) uured[wv] = uu_acc * 0.25f;   // / 4 dup over g
    __syncthreads();

    if (tid < 64) {
        const float t = sred[0][tid] + sred[1][tid] + sred[2][tid] + sred[3][tid];
        atomicAdd(&acc[tid], t);
    }
    if (tid == 0)
        atomicAdd(&acc[64], uured[0] + uured[1] + uured[2] + uured[3]);
}

__global__ void finalize_k(const float* __restrict__ acc, float* __restrict__ out)
{
    float s = acc[threadIdx.x];
    float d = s * s;
#pragma unroll
    for (int off = 32; off > 0; off >>= 1)
        d += __shfl_xor(d, off, 64);
    if (threadIdx.x == 0)
        out[0] = 0.5f * (d - acc[64]) / (float)NROWS;
}

extern "C" void kernel_launch(void* const* d_in, const int* in_sizes, int n_in,
                              void* d_out, int out_size, void* d_ws, size_t ws_size,
                              hipStream_t stream)
{
    const float* x  = (const float*)d_in[0];
    const float* W1 = (const float*)d_in[1];
    const float* b1 = (const float*)d_in[2];
    const float* W2 = (const float*)d_in[3];
    const float* b2 = (const float*)d_in[4];
    const float* W3 = (const float*)d_in[5];
    const float* b3 = (const float*)d_in[6];

    char* ws = (char*)d_ws;
    float*          acc = (float*)ws;                      // 1 KB
    unsigned short* w1f = (unsigned short*)(ws + 1024);    // 24576 B
    unsigned short* w2f = (unsigned short*)(ws + 25600);   // 15360 B
    unsigned short* w3f = (unsigned short*)(ws + 40960);   // 12288 B
    float*          b1p = (float*)(ws + 53248);            // 384 B
    float*          b2p = (float*)(ws + 53632);            // 320 B
    float*          b3p = (float*)(ws + 53952);            // 256 B

    hipMemsetAsync(acc, 0, 1024, stream);
    repack<<<52, 64, 0, stream>>>(W1, b1, W2, b2, W3, b3, w1f, w2f, w3f, b1p, b2p, b3p);
    // 1024 blocks x 4 waves x 2 passes x 32 samples = 262144 rows
    mlp_main<<<NROWS / (4 * PASSES * 32), 256, 0, stream>>>(
        x, (const f32x4*)(ws + 1024), acc);
    finalize_k<<<1, 64, 0, stream>>>(acc, (float*)d_out);
}

// Round 7
// 69.635 us; speedup vs baseline: 1.2379x; 1.2379x over previous
//
#include <hip/hip_runtime.h>

typedef float  f32x4  __attribute__((ext_vector_type(4)));
typedef short  s16x8  __attribute__((ext_vector_type(8)));
typedef short  s16x4  __attribute__((ext_vector_type(4)));

#define NROWS (2048 * 128)
#define RPB 128          // rows per block-tile (4 waves x 32)
#define TILES 4          // row-tiles per block
#define HS 104           // act LDS stride in shorts
#define EPSF 1e-8f

union Frag { s16x8 v; unsigned short u[8]; };

// fp32 -> bf16 RTNE (verified R3-R6, absmax 0.0)
__device__ __forceinline__ unsigned short f2bf(float f) {
    unsigned int u = __float_as_uint(f);
    u += 0x7fffu + ((u >> 16) & 1u);
    return (unsigned short)(u >> 16);
}

// ---------------------------------------------------------------------------
// Pre-kernel: repack weights to bf16 MFMA B-fragment order (unchanged).
// Contiguous in ws: w1(24576) w2(15360) w3(12288) b1(384) b2(320) b3(256).
// ---------------------------------------------------------------------------
__global__ void repack(const float* __restrict__ W1, const float* __restrict__ b1,
                       const float* __restrict__ W2, const float* __restrict__ b2,
                       const float* __restrict__ W3, const float* __restrict__ b3,
                       unsigned short* __restrict__ w1f, unsigned short* __restrict__ w2f,
                       unsigned short* __restrict__ w3f,
                       float* __restrict__ b1p, float* __restrict__ b2p,
                       float* __restrict__ b3p)
{
    const int b = blockIdx.x;
    const int l = threadIdx.x;      // 64 threads
    const int g = l >> 4, sl = l & 15;

    if (b < 24) {                   // W1: nt = b>>2, ks = b&3
        const int nt = b >> 2, ks = b & 3;
        const int o = nt * 16 + sl, kb = ks * 32 + g * 8;
        s16x8 v;
#pragma unroll
        for (int j = 0; j < 8; ++j) v[j] = (short)f2bf(W1[o * 128 + kb + j]);
        *(s16x8*)&w1f[b * 512 + l * 8] = v;
    } else if (b < 39) {            // W2 (out padded 72->80)
        const int f = b - 24, nt = f / 3, ks = f % 3;
        const int o = nt * 16 + sl, kb = ks * 32 + g * 8;
        s16x8 v;
#pragma unroll
        for (int j = 0; j < 8; ++j)
            v[j] = (short)((o < 72) ? f2bf(W2[o * 96 + kb + j]) : 0);
        *(s16x8*)&w2f[f * 512 + l * 8] = v;
    } else if (b < 51) {            // W3 (k padded 72->96)
        const int f = b - 39, nt = f / 3, ks = f % 3;
        const int o = nt * 16 + sl, kb = ks * 32 + g * 8;
        s16x8 v;
#pragma unroll
        for (int j = 0; j < 8; ++j)
            v[j] = (short)((kb + j < 72) ? f2bf(W3[o * 72 + kb + j]) : 0);
        *(s16x8*)&w3f[f * 512 + l * 8] = v;
    } else {                        // biases, zero-padded
        for (int i = l; i < 240; i += 64) {
            if (i < 96)       b1p[i] = b1[i];
            else if (i < 176) { int o = i - 96; b2p[o] = (o < 72) ? b2[o] : 0.f; }
            else              b3p[i - 176] = b3[i - 176];
        }
    }
}

// ---------------------------------------------------------------------------
// Main (R5 structure). 512 blocks x 256 thr; stage 53.2 KB weights->LDS once,
// then 4 row-tiles of 128 rows, x prefetched one tile ahead in registers.
// LDS 80.9 KB -> 2 blocks/CU -> 2 waves/SIMD. amdgpu_waves_per_eu(2,2) pins
// the allocator's occupancy target to that LDS-imposed ceiling, unlocking the
// full 256-VGPR/wave budget: R5's 21.6 MB of scratch spill (VGPR clamped to
// 128 by the default occupancy heuristic) must disappear.
// ---------------------------------------------------------------------------
__global__ __launch_bounds__(256, 2) __attribute__((amdgpu_waves_per_eu(2, 2)))
void mlp_main(const float* __restrict__ x,
              const f32x4* __restrict__ wsrc,   // 3324 x 16 B = weights+biases
              float* __restrict__ acc /* [65]: s[64], uu */)
{
    __shared__ __align__(16) unsigned char  wb[53184];           // w1|w2|w3|b1|b2|b3
    __shared__ __align__(16) unsigned short act[4][2][16][HS];   // 26.6 KB wave-private
    __shared__ float sred[4][64];
    __shared__ float uured[4];

    const unsigned short* w1L = (const unsigned short*)wb;   // 24 frags
    const unsigned short* w2L = w1L + 12288;                 // 15 frags
    const unsigned short* w3L = w1L + 19968;                 // 12 frags
    const float* b1L = (const float*)(wb + 52224);           // 96
    const float* b2L = b1L + 96;                             // 80
    const float* b3L = b1L + 176;                            // 64

    const int tid  = threadIdx.x;
    const int lane = tid & 63;
    const int wv   = tid >> 6;
    const int g    = lane >> 4;
    const int sl   = lane & 15;

    // lane-fixed part of the x address: row (st*16+sl), col (ks*32+g*8)
    auto loadx = [&](f32x4 (&xp)[16], int tile) {
        const float* xw = x + ((size_t)(blockIdx.x * TILES + tile) * RPB + wv * 32) * 128;
#pragma unroll
        for (int st = 0; st < 2; ++st)
#pragma unroll
            for (int ks = 0; ks < 4; ++ks) {
                const float* p = xw + (st * 16 + sl) * 128 + ks * 32 + g * 8;
                xp[st * 8 + ks * 2 + 0] = *(const f32x4*)p;
                xp[st * 8 + ks * 2 + 1] = *(const f32x4*)(p + 4);
            }
    };

    // ---- issue tile-0 x loads BEFORE weight staging (overlap) ----
    f32x4 xp[16];
    loadx(xp, 0);

    // ---- stage weights + biases to LDS (53184 B = 3324 f32x4) ----
    for (int i = tid; i < 3324; i += 256)
        ((f32x4*)wb)[i] = wsrc[i];
    __syncthreads();                      // weights visible to all waves

    float uu_part = 0.f;
    float s_part[4] = {0.f, 0.f, 0.f, 0.f};

    for (int t = 0; t < TILES; ++t) {
        // convert current tile's x to A-frags
        Frag A1[2][4];
#pragma unroll
        for (int st = 0; st < 2; ++st)
#pragma unroll
            for (int ks = 0; ks < 4; ++ks)
#pragma unroll
                for (int j = 0; j < 4; ++j) {
                    A1[st][ks].u[j]     = f2bf(xp[st * 8 + ks * 2 + 0][j]);
                    A1[st][ks].u[4 + j] = f2bf(xp[st * 8 + ks * 2 + 1][j]);
                }

        // prefetch next tile (independent of everything below)
        if (t + 1 < TILES) loadx(xp, t + 1);

        // ================= layer 1: 128 -> 96 =================
        f32x4 D1[2][6];
#pragma unroll
        for (int nt = 0; nt < 6; ++nt) {
            const float bb = b1L[nt * 16 + sl];
            D1[0][nt] = (f32x4){bb, bb, bb, bb};
            D1[1][nt] = D1[0][nt];
        }
#pragma unroll
        for (int ks = 0; ks < 4; ++ks)
#pragma unroll
            for (int nt = 0; nt < 6; ++nt) {
                const s16x8 B = *(const s16x8*)&w1L[(nt * 4 + ks) * 512 + lane * 8];
                D1[0][nt] = __builtin_amdgcn_mfma_f32_16x16x32_bf16(A1[0][ks].v, B, D1[0][nt], 0, 0, 0);
                D1[1][nt] = __builtin_amdgcn_mfma_f32_16x16x32_bf16(A1[1][ks].v, B, D1[1][nt], 0, 0, 0);
            }
#pragma unroll
        for (int st = 0; st < 2; ++st)
#pragma unroll
            for (int nt = 0; nt < 6; ++nt)
#pragma unroll
                for (int r = 0; r < 4; ++r)
                    act[wv][st][g * 4 + r][nt * 16 + sl] = f2bf(fmaxf(D1[st][nt][r], 0.f));

        // layer-2 A-frags (wave-private LDS; compiler inserts lgkmcnt)
        Frag A2[2][3];
#pragma unroll
        for (int st = 0; st < 2; ++st)
#pragma unroll
            for (int ks = 0; ks < 3; ++ks)
                A2[st][ks].v = *(const s16x8*)&act[wv][st][sl][ks * 32 + g * 8];

        // zero pad feats 80..95 (clobbered each tile by h1 writes)
        {
            const s16x4 z = (s16x4){0, 0, 0, 0};
            *(s16x4*)&act[wv][0][sl][80 + g * 4] = z;
            *(s16x4*)&act[wv][1][sl][80 + g * 4] = z;
        }

        // ================= layer 2: 96 -> 72 (pad 80) =================
        f32x4 D2[2][5];
#pragma unroll
        for (int nt = 0; nt < 5; ++nt) {
            const float bb = b2L[nt * 16 + sl];
            D2[0][nt] = (f32x4){bb, bb, bb, bb};
            D2[1][nt] = D2[0][nt];
        }
#pragma unroll
        for (int ks = 0; ks < 3; ++ks)
#pragma unroll
            for (int nt = 0; nt < 5; ++nt) {
                const s16x8 B = *(const s16x8*)&w2L[(nt * 3 + ks) * 512 + lane * 8];
                D2[0][nt] = __builtin_amdgcn_mfma_f32_16x16x32_bf16(A2[0][ks].v, B, D2[0][nt], 0, 0, 0);
                D2[1][nt] = __builtin_amdgcn_mfma_f32_16x16x32_bf16(A2[1][ks].v, B, D2[1][nt], 0, 0, 0);
            }
#pragma unroll
        for (int st = 0; st < 2; ++st)
#pragma unroll
            for (int nt = 0; nt < 5; ++nt)
#pragma unroll
                for (int r = 0; r < 4; ++r)
                    act[wv][st][g * 4 + r][nt * 16 + sl] = f2bf(fmaxf(D2[st][nt][r], 0.f));

        // layer-3 A-frags
        Frag A3[2][3];
#pragma unroll
        for (int st = 0; st < 2; ++st)
#pragma unroll
            for (int ks = 0; ks < 3; ++ks)
                A3[st][ks].v = *(const s16x8*)&act[wv][st][sl][ks * 32 + g * 8];

        // ================= layer 3: 72 (pad 96) -> 64 =================
        f32x4 D3[2][4];
#pragma unroll
        for (int nt = 0; nt < 4; ++nt) {
            const float bb = b3L[nt * 16 + sl];
            D3[0][nt] = (f32x4){bb, bb, bb, bb};
            D3[1][nt] = D3[0][nt];
        }
#pragma unroll
        for (int ks = 0; ks < 3; ++ks)
#pragma unroll
            for (int nt = 0; nt < 4; ++nt) {
                const s16x8 B = *(const s16x8*)&w3L[(nt * 3 + ks) * 512 + lane * 8];
                D3[0][nt] = __builtin_amdgcn_mfma_f32_16x16x32_bf16(A3[0][ks].v, B, D3[0][nt], 0, 0, 0);
                D3[1][nt] = __builtin_amdgcn_mfma_f32_16x16x32_bf16(A3[1][ks].v, B, D3[1][nt], 0, 0, 0);
            }

        // ===== epilogue: row norm; accumulate s/uu across tiles =====
#pragma unroll
        for (int st = 0; st < 2; ++st) {
            float ffr[4];
#pragma unroll
            for (int r = 0; r < 4; ++r) {
                float a = 0.f;
#pragma unroll
                for (int nt = 0; nt < 4; ++nt)
                    a = fmaf(D3[st][nt][r], D3[st][nt][r], a);
                ffr[r] = a;
            }
#pragma unroll
            for (int r = 0; r < 4; ++r) {
                ffr[r] += __shfl_xor(ffr[r], 1, 64);
                ffr[r] += __shfl_xor(ffr[r], 2, 64);
                ffr[r] += __shfl_xor(ffr[r], 4, 64);
                ffr[r] += __shfl_xor(ffr[r], 8, 64);
            }
            float inv[4];
#pragma unroll
            for (int r = 0; r < 4; ++r) {
                inv[r] = 1.f / fmaxf(sqrtf(ffr[r]), EPSF);
                uu_part = fmaf(ffr[r] * inv[r], inv[r], uu_part);  // dup x16 over sl
            }
#pragma unroll
            for (int nt = 0; nt < 4; ++nt)
#pragma unroll
                for (int r = 0; r < 4; ++r)
                    s_part[nt] = fmaf(D3[st][nt][r], inv[r], s_part[nt]);
        }
    }

    // cross-g reduction (once, after all tiles)
#pragma unroll
    for (int nt = 0; nt < 4; ++nt) {
        s_part[nt] += __shfl_xor(s_part[nt], 16, 64);
        s_part[nt] += __shfl_xor(s_part[nt], 32, 64);
    }
    uu_part += __shfl_xor(uu_part, 16, 64);
    uu_part += __shfl_xor(uu_part, 32, 64);

    if (g == 0) {
#pragma unroll
        for (int nt = 0; nt < 4; ++nt) sred[wv][nt * 16 + sl] = s_part[nt];
    }
    if (lane == 0) uured[wv] = uu_part * 0.0625f;
    __syncthreads();

    if (tid < 64) {
        const float t = sred[0][tid] + sred[1][tid] + sred[2][tid] + sred[3][tid];
        atomicAdd(&acc[tid], t);
    }
    if (tid == 0)
        atomicAdd(&acc[64], uured[0] + uured[1] + uured[2] + uured[3]);
}

__global__ void finalize_k(const float* __restrict__ acc, float* __restrict__ out)
{
    float s = acc[threadIdx.x];
    float d = s * s;
#pragma unroll
    for (int off = 32; off > 0; off >>= 1)
        d += __shfl_xor(d, off, 64);
    if (threadIdx.x == 0)
        out[0] = 0.5f * (d - acc[64]) / (float)NROWS;
}

extern "C" void kernel_launch(void* const* d_in, const int* in_sizes, int n_in,
                              void* d_out, int out_size, void* d_ws, size_t ws_size,
                              hipStream_t stream)
{
    const float* x  = (const float*)d_in[0];
    const float* W1 = (const float*)d_in[1];
    const float* b1 = (const float*)d_in[2];
    const float* W2 = (const float*)d_in[3];
    const float* b2 = (const float*)d_in[4];
    const float* W3 = (const float*)d_in[5];
    const float* b3 = (const float*)d_in[6];

    char* ws = (char*)d_ws;
    float*          acc = (float*)ws;                      // 1 KB
    unsigned short* w1f = (unsigned short*)(ws + 1024);    // 24576 B
    unsigned short* w2f = (unsigned short*)(ws + 25600);   // 15360 B
    unsigned short* w3f = (unsigned short*)(ws + 40960);   // 12288 B
    float*          b1p = (float*)(ws + 53248);            // 384 B
    float*          b2p = (float*)(ws + 53632);            // 320 B
    float*          b3p = (float*)(ws + 53952);            // 256 B

    hipMemsetAsync(acc, 0, 1024, stream);
    repack<<<52, 64, 0, stream>>>(W1, b1, W2, b2, W3, b3, w1f, w2f, w3f, b1p, b2p, b3p);
    mlp_main<<<NROWS / (RPB * TILES), 256, 0, stream>>>(
        x, (const f32x4*)(ws + 1024), acc);
    finalize_k<<<1, 64, 0, stream>>>(acc, (float*)d_out);
}